// Round 1
// baseline (192.686 us; speedup 1.0000x reference)
//
#include <hip/hip_runtime.h>
#include <math.h>

#define CORNER_L 0.05f

typedef float f4 __attribute__((ext_vector_type(4)));

constexpr int THREADS = 256;
constexpr int GROUPS  = 1024;
constexpr int CQ = 3, PQ = 2;                    // class:pose block ratio per group
constexpr int CBLOCKS = CQ * GROUPS;             // 3072
constexpr int PBLOCKS = PQ * GROUPS;             // 2048 (524288 threads, 2 elem/thread)
constexpr int TOTAL_BLOCKS = CBLOCKS + PBLOCKS;  // 5120

// Fully scalar, pointer-free pose distance for one element pair.
__device__ __forceinline__ float pose_elem(
    float py, float pp_, float pr, float ptx, float pty, float ptz,
    float ty, float tp_, float tr, float ttx, float tty, float ttz)
{
    float sy1 = __sinf(py),  cy1 = __cosf(py);
    float sp1 = __sinf(pp_), cp1 = __cosf(pp_);
    float sr1 = __sinf(pr),  cr1 = __cosf(pr);
    float sy2 = __sinf(ty),  cy2 = __cosf(ty);
    float sp2 = __sinf(tp_), cp2 = __cosf(tp_);
    float sr2 = __sinf(tr),  cr2 = __cosf(tr);

    float a0 = CORNER_L * (cy1 * cp1 - cy2 * cp2);
    float a1 = CORNER_L * ((cy1 * sp1 * sr1 - sy1 * cr1) - (cy2 * sp2 * sr2 - sy2 * cr2));
    float a2 = CORNER_L * ((cy1 * sp1 * cr1 + sy1 * sr1) - (cy2 * sp2 * cr2 + sy2 * sr2));
    float b0 = CORNER_L * (sy1 * cp1 - sy2 * cp2);
    float b1 = CORNER_L * ((sy1 * sp1 * sr1 + cy1 * cr1) - (sy2 * sp2 * sr2 + cy2 * cr2));
    float b2 = CORNER_L * ((sy1 * sp1 * cr1 - cy1 * sr1) - (sy2 * sp2 * cr2 - cy2 * sr2));
    float c0 = CORNER_L * (sp2 - sp1);
    float c1 = CORNER_L * (cp1 * sr1 - cp2 * sr2);
    float c2 = CORNER_L * (cp1 * cr1 - cp2 * cr2);
    float dtx = ptx - ttx;
    float dty = pty - tty;
    float dtz = ptz - ttz;

    float nsum = 0.0f;
    #pragma unroll
    for (int s = 0; s < 8; ++s) {
        float sx = (s & 4) ? 1.0f : -1.0f;
        float sy = (s & 2) ? 1.0f : -1.0f;
        float sz = (s & 1) ? 1.0f : -1.0f;
        float d0 = sx * a0 + sy * a1 + sz * a2 + dtx;
        float d1 = sx * b0 + sy * b1 + sz * b2 + dty;
        float d2 = sx * c0 + sy * c1 + sz * c2 + dtz;
        nsum += __builtin_amdgcn_sqrtf(d0 * d0 + d1 * d1 + d2 * d2);
    }
    return nsum;
}

// Block-specialized fused kernel: per group of 5 blocks, 3 run the clean
// grid-stride class-MSE stream, 2 run the one-shot pose path. Both types
// co-resident -> pose trig hides under class streaming; BW fully shared.
// Loads are PLAIN (cached): inputs total 176 MiB < 256 MiB Infinity Cache
// and are re-read on every replay -- nt (evict-first) loads forced full
// HBM re-fetch each iteration; cached loads let warm replays hit L3.
__global__ __launch_bounds__(THREADS) void pose_loss_fused(
    const f4* __restrict__ pp4, const f4* __restrict__ pc4,
    const f4* __restrict__ tp4, const f4* __restrict__ tc4,
    float* __restrict__ ws, int n4)
{
    const int tid = threadIdx.x;
    const int g   = blockIdx.x;
    const int grp = g / 5;
    const int r   = g - grp * 5;

    float acc = 0.0f;
    int out_idx;

    if (r < CQ) {
        // ---------- class MSE: clean grid-stride stream ----------
        const int cb = grp * CQ + r;                 // 0..3071
        const size_t G = (size_t)CBLOCKS * THREADS;
        for (size_t i = (size_t)cb * THREADS + tid; i < (size_t)n4; i += G) {
            f4 p = pc4[i];
            f4 t = tc4[i];
            f4 d = p - t;
            acc += d.x * d.x + d.y * d.y + d.z * d.z + d.w * d.w;
        }
        out_idx = cb;
    } else {
        // ---------- pose: one-shot 3 f4/array per thread, 2 elements ----------
        const int pb = grp * PQ + (r - CQ);          // 0..2047
        const size_t gtid = (size_t)pb * THREADS + tid;
        const size_t f = gtid * 3;
        f4 P0 = pp4[f];
        f4 P1 = pp4[f + 1];
        f4 P2 = pp4[f + 2];
        f4 T0 = tp4[f];
        f4 T1 = tp4[f + 1];
        f4 T2 = tp4[f + 2];
        acc += pose_elem(P0.x, P0.y, P0.z, P0.w, P1.x, P1.y,
                         T0.x, T0.y, T0.z, T0.w, T1.x, T1.y);
        acc += pose_elem(P1.z, P1.w, P2.x, P2.y, P2.z, P2.w,
                         T1.z, T1.w, T2.x, T2.y, T2.z, T2.w);
        out_idx = CBLOCKS + pb;
    }

    // ---------- common block reduction ----------
    #pragma unroll
    for (int off = 32; off > 0; off >>= 1) acc += __shfl_down(acc, off);
    __shared__ float red[4];
    const int lane = tid & 63, wave = tid >> 6;
    if (lane == 0) red[wave] = acc;
    __syncthreads();
    if (tid == 0) ws[out_idx] = red[0] + red[1] + red[2] + red[3];
}

// finalize: ws[0..CBLOCKS) = class partials, ws[CBLOCKS..TOTAL) = pose partials
__global__ __launch_bounds__(THREADS) void pose_loss_finalize(
    const float* __restrict__ ws, float* __restrict__ out,
    float inv_pose, float inv_class)
{
    float c = 0.0f, p = 0.0f;
    for (int k = threadIdx.x; k < CBLOCKS; k += THREADS) c += ws[k];
    for (int k = threadIdx.x; k < PBLOCKS; k += THREADS) p += ws[CBLOCKS + k];
    #pragma unroll
    for (int off = 32; off > 0; off >>= 1) {
        p += __shfl_down(p, off);
        c += __shfl_down(c, off);
    }
    __shared__ float r_p[4], r_c[4];
    const int lane = threadIdx.x & 63, wave = threadIdx.x >> 6;
    if (lane == 0) { r_p[wave] = p; r_c[wave] = c; }
    __syncthreads();
    if (threadIdx.x == 0) {
        float lp = (r_p[0] + r_p[1] + r_p[2] + r_p[3]) * inv_pose;
        float lc = (r_c[0] + r_c[1] + r_c[2] + r_c[3]) * inv_class;
        out[0] = lp + lc;
        out[1] = lp;
        out[2] = lc;
    }
}

extern "C" void kernel_launch(void* const* d_in, const int* in_sizes, int n_in,
                              void* d_out, int out_size, void* d_ws, size_t ws_size,
                              hipStream_t stream) {
    const f4* pred_pose    = (const f4*)d_in[0];
    const f4* pred_class   = (const f4*)d_in[1];
    const f4* target_pose  = (const f4*)d_in[2];
    const f4* target_class = (const f4*)d_in[3];
    float* out = (float*)d_out;
    float* ws  = (float*)d_ws;

    const int B  = in_sizes[0] / 6;
    const int n4 = B * 4;   // float4 count per class array

    pose_loss_fused<<<TOTAL_BLOCKS, THREADS, 0, stream>>>(
        pred_pose, pred_class, target_pose, target_class, ws, n4);

    const float inv_pose  = 1.0f / (8.0f  * (float)B);
    const float inv_class = 1.0f / (16.0f * (float)B);
    pose_loss_finalize<<<1, THREADS, 0, stream>>>(ws, out, inv_pose, inv_class);
}

// Round 2
// 175.811 us; speedup vs baseline: 1.0960x; 1.0960x over previous
//
#include <hip/hip_runtime.h>
#include <math.h>

#define CORNER_L 0.05f

typedef float f4 __attribute__((ext_vector_type(4)));

constexpr int THREADS = 256;
constexpr int GROUPS  = 1024;
constexpr int CQ = 3, PQ = 2;                    // class:pose block ratio per group
constexpr int CBLOCKS = CQ * GROUPS;             // 3072
constexpr int PBLOCKS = PQ * GROUPS;             // 2048 (524288 threads, 2 elem/thread)
constexpr int TOTAL_BLOCKS = CBLOCKS + PBLOCKS;  // 5120

// Fully scalar, pointer-free pose distance for one element pair.
__device__ __forceinline__ float pose_elem(
    float py, float pp_, float pr, float ptx, float pty, float ptz,
    float ty, float tp_, float tr, float ttx, float tty, float ttz)
{
    float sy1 = __sinf(py),  cy1 = __cosf(py);
    float sp1 = __sinf(pp_), cp1 = __cosf(pp_);
    float sr1 = __sinf(pr),  cr1 = __cosf(pr);
    float sy2 = __sinf(ty),  cy2 = __cosf(ty);
    float sp2 = __sinf(tp_), cp2 = __cosf(tp_);
    float sr2 = __sinf(tr),  cr2 = __cosf(tr);

    float a0 = CORNER_L * (cy1 * cp1 - cy2 * cp2);
    float a1 = CORNER_L * ((cy1 * sp1 * sr1 - sy1 * cr1) - (cy2 * sp2 * sr2 - sy2 * cr2));
    float a2 = CORNER_L * ((cy1 * sp1 * cr1 + sy1 * sr1) - (cy2 * sp2 * cr2 + sy2 * sr2));
    float b0 = CORNER_L * (sy1 * cp1 - sy2 * cp2);
    float b1 = CORNER_L * ((sy1 * sp1 * sr1 + cy1 * cr1) - (sy2 * sp2 * sr2 + cy2 * cr2));
    float b2 = CORNER_L * ((sy1 * sp1 * cr1 - cy1 * sr1) - (sy2 * sp2 * cr2 - cy2 * sr2));
    float c0 = CORNER_L * (sp2 - sp1);
    float c1 = CORNER_L * (cp1 * sr1 - cp2 * sr2);
    float c2 = CORNER_L * (cp1 * cr1 - cp2 * cr2);
    float dtx = ptx - ttx;
    float dty = pty - tty;
    float dtz = ptz - ttz;

    float nsum = 0.0f;
    #pragma unroll
    for (int s = 0; s < 8; ++s) {
        float sx = (s & 4) ? 1.0f : -1.0f;
        float sy = (s & 2) ? 1.0f : -1.0f;
        float sz = (s & 1) ? 1.0f : -1.0f;
        float d0 = sx * a0 + sy * a1 + sz * a2 + dtx;
        float d1 = sx * b0 + sy * b1 + sz * b2 + dty;
        float d2 = sx * c0 + sy * c1 + sz * c2 + dtz;
        nsum += __builtin_amdgcn_sqrtf(d0 * d0 + d1 * d1 + d2 * d2);
    }
    return nsum;
}

// Block-specialized fused kernel: per group of 5 blocks, 3 run the class-MSE
// stream, 2 run the one-shot pose path. Both types co-resident -> pose trig
// hides under class streaming; BW fully shared.
//
// NT loads are REQUIRED here (measured round 1): plain cached loads cut
// FETCH_SIZE to ~93 MB (L3 absorbed half) but the fused kernel slowed
// 40 -> 69 us (2.7 TB/s effective) -- the L2 allocate/evict path throttles
// a 176 MB stream. nt (evict-first) sustains >=4.6 TB/s. Keep nt.
//
// Class loop is manually unrolled x2 for MLP: 4 independent 16B loads in
// flight per thread instead of 2. Per-thread element order and accumulation
// order are IDENTICAL to the verified single-step loop (bitwise-same block
// partials) -- only load issue is batched.
__global__ __launch_bounds__(THREADS) void pose_loss_fused(
    const f4* __restrict__ pp4, const f4* __restrict__ pc4,
    const f4* __restrict__ tp4, const f4* __restrict__ tc4,
    float* __restrict__ ws, int n4)
{
    const int tid = threadIdx.x;
    const int g   = blockIdx.x;
    const int grp = g / 5;
    const int r   = g - grp * 5;

    float acc = 0.0f;
    int out_idx;

    if (r < CQ) {
        // ---------- class MSE: grid-stride stream, unroll x2 ----------
        const int cb = grp * CQ + r;                 // 0..3071
        const size_t G = (size_t)CBLOCKS * THREADS;
        size_t i = (size_t)cb * THREADS + tid;
        for (; i + G < (size_t)n4; i += 2 * G) {
            f4 p0 = __builtin_nontemporal_load(pc4 + i);
            f4 t0 = __builtin_nontemporal_load(tc4 + i);
            f4 p1 = __builtin_nontemporal_load(pc4 + i + G);
            f4 t1 = __builtin_nontemporal_load(tc4 + i + G);
            f4 d0 = p0 - t0;
            f4 d1 = p1 - t1;
            acc += d0.x * d0.x + d0.y * d0.y + d0.z * d0.z + d0.w * d0.w;
            acc += d1.x * d1.x + d1.y * d1.y + d1.z * d1.z + d1.w * d1.w;
        }
        if (i < (size_t)n4) {
            f4 p = __builtin_nontemporal_load(pc4 + i);
            f4 t = __builtin_nontemporal_load(tc4 + i);
            f4 d = p - t;
            acc += d.x * d.x + d.y * d.y + d.z * d.z + d.w * d.w;
        }
        out_idx = cb;
    } else {
        // ---------- pose: one-shot 3 f4/array per thread, 2 elements ----------
        const int pb = grp * PQ + (r - CQ);          // 0..2047
        const size_t gtid = (size_t)pb * THREADS + tid;
        const size_t f = gtid * 3;
        f4 P0 = __builtin_nontemporal_load(pp4 + f);
        f4 P1 = __builtin_nontemporal_load(pp4 + f + 1);
        f4 P2 = __builtin_nontemporal_load(pp4 + f + 2);
        f4 T0 = __builtin_nontemporal_load(tp4 + f);
        f4 T1 = __builtin_nontemporal_load(tp4 + f + 1);
        f4 T2 = __builtin_nontemporal_load(tp4 + f + 2);
        acc += pose_elem(P0.x, P0.y, P0.z, P0.w, P1.x, P1.y,
                         T0.x, T0.y, T0.z, T0.w, T1.x, T1.y);
        acc += pose_elem(P1.z, P1.w, P2.x, P2.y, P2.z, P2.w,
                         T1.z, T1.w, T2.x, T2.y, T2.z, T2.w);
        out_idx = CBLOCKS + pb;
    }

    // ---------- common block reduction ----------
    #pragma unroll
    for (int off = 32; off > 0; off >>= 1) acc += __shfl_down(acc, off);
    __shared__ float red[4];
    const int lane = tid & 63, wave = tid >> 6;
    if (lane == 0) red[wave] = acc;
    __syncthreads();
    if (tid == 0) ws[out_idx] = red[0] + red[1] + red[2] + red[3];
}

// finalize: ws[0..CBLOCKS) = class partials, ws[CBLOCKS..TOTAL) = pose partials
__global__ __launch_bounds__(THREADS) void pose_loss_finalize(
    const float* __restrict__ ws, float* __restrict__ out,
    float inv_pose, float inv_class)
{
    float c = 0.0f, p = 0.0f;
    for (int k = threadIdx.x; k < CBLOCKS; k += THREADS) c += ws[k];
    for (int k = threadIdx.x; k < PBLOCKS; k += THREADS) p += ws[CBLOCKS + k];
    #pragma unroll
    for (int off = 32; off > 0; off >>= 1) {
        p += __shfl_down(p, off);
        c += __shfl_down(c, off);
    }
    __shared__ float r_p[4], r_c[4];
    const int lane = threadIdx.x & 63, wave = threadIdx.x >> 6;
    if (lane == 0) { r_p[wave] = p; r_c[wave] = c; }
    __syncthreads();
    if (threadIdx.x == 0) {
        float lp = (r_p[0] + r_p[1] + r_p[2] + r_p[3]) * inv_pose;
        float lc = (r_c[0] + r_c[1] + r_c[2] + r_c[3]) * inv_class;
        out[0] = lp + lc;
        out[1] = lp;
        out[2] = lc;
    }
}

extern "C" void kernel_launch(void* const* d_in, const int* in_sizes, int n_in,
                              void* d_out, int out_size, void* d_ws, size_t ws_size,
                              hipStream_t stream) {
    const f4* pred_pose    = (const f4*)d_in[0];
    const f4* pred_class   = (const f4*)d_in[1];
    const f4* target_pose  = (const f4*)d_in[2];
    const f4* target_class = (const f4*)d_in[3];
    float* out = (float*)d_out;
    float* ws  = (float*)d_ws;

    const int B  = in_sizes[0] / 6;
    const int n4 = B * 4;   // float4 count per class array

    pose_loss_fused<<<TOTAL_BLOCKS, THREADS, 0, stream>>>(
        pred_pose, pred_class, target_pose, target_class, ws, n4);

    const float inv_pose  = 1.0f / (8.0f  * (float)B);
    const float inv_class = 1.0f / (16.0f * (float)B);
    pose_loss_finalize<<<1, THREADS, 0, stream>>>(ws, out, inv_pose, inv_class);
}

// Round 3
// 174.162 us; speedup vs baseline: 1.1064x; 1.0095x over previous
//
#include <hip/hip_runtime.h>
#include <math.h>

#define CORNER_L 0.05f

typedef float f4 __attribute__((ext_vector_type(4)));

constexpr int THREADS = 256;
constexpr int BLOCKS  = 2048;   // 8 blocks/CU * 256 CU -> fully co-resident, zero churn
constexpr int CTRIPS  = 8;      // 4194304 f4 / 524288 threads = exactly 8 pairs/thread

// Fully scalar, pointer-free pose distance for one element pair.
__device__ __forceinline__ float pose_elem(
    float py, float pp_, float pr, float ptx, float pty, float ptz,
    float ty, float tp_, float tr, float ttx, float tty, float ttz)
{
    float sy1 = __sinf(py),  cy1 = __cosf(py);
    float sp1 = __sinf(pp_), cp1 = __cosf(pp_);
    float sr1 = __sinf(pr),  cr1 = __cosf(pr);
    float sy2 = __sinf(ty),  cy2 = __cosf(ty);
    float sp2 = __sinf(tp_), cp2 = __cosf(tp_);
    float sr2 = __sinf(tr),  cr2 = __cosf(tr);

    float a0 = CORNER_L * (cy1 * cp1 - cy2 * cp2);
    float a1 = CORNER_L * ((cy1 * sp1 * sr1 - sy1 * cr1) - (cy2 * sp2 * sr2 - sy2 * cr2));
    float a2 = CORNER_L * ((cy1 * sp1 * cr1 + sy1 * sr1) - (cy2 * sp2 * cr2 + sy2 * sr2));
    float b0 = CORNER_L * (sy1 * cp1 - sy2 * cp2);
    float b1 = CORNER_L * ((sy1 * sp1 * sr1 + cy1 * cr1) - (sy2 * sp2 * sr2 + cy2 * cr2));
    float b2 = CORNER_L * ((sy1 * sp1 * cr1 - cy1 * sr1) - (sy2 * sp2 * cr2 - cy2 * sr2));
    float c0 = CORNER_L * (sp2 - sp1);
    float c1 = CORNER_L * (cp1 * sr1 - cp2 * sr2);
    float c2 = CORNER_L * (cp1 * cr1 - cp2 * cr2);
    float dtx = ptx - ttx;
    float dty = pty - tty;
    float dtz = ptz - ttz;

    float nsum = 0.0f;
    #pragma unroll
    for (int s = 0; s < 8; ++s) {
        float sx = (s & 4) ? 1.0f : -1.0f;
        float sy = (s & 2) ? 1.0f : -1.0f;
        float sz = (s & 1) ? 1.0f : -1.0f;
        float d0 = sx * a0 + sy * a1 + sz * a2 + dtx;
        float d1 = sx * b0 + sy * b1 + sz * b2 + dty;
        float d2 = sx * c0 + sy * c1 + sz * c2 + dtz;
        nsum += __builtin_amdgcn_sqrtf(d0 * d0 + d1 * d1 + d2 * d2);
    }
    return nsum;
}

// Uniform exactly-resident kernel: every thread streams exactly 8 class
// f4-pairs (no tail, compile-time trips) AND computes the same 2 pose
// elements the old pose-block mapping assigned (pose partials bitwise
// identical to the verified split kernel). Pose loads issue first; pose
// trig is sandwiched between class trips 0-3 and 4-7 so the trans-pipe
// work hides under in-flight nt class loads within the same thread.
//
// NT loads REQUIRED (measured round 1): cached loads throttle this 176 MiB
// stream through L2 allocate/evict (2.7 TB/s vs >=4.6 TB/s with nt).
__global__ __launch_bounds__(THREADS) void pose_loss_fused(
    const f4* __restrict__ pp4, const f4* __restrict__ pc4,
    const f4* __restrict__ tp4, const f4* __restrict__ tc4,
    float* __restrict__ ws)
{
    const int tid = threadIdx.x;
    const int b   = blockIdx.x;
    const size_t gtid = (size_t)b * THREADS + tid;
    constexpr size_t G = (size_t)BLOCKS * THREADS;   // 524288

    // ---------- issue pose loads first (deepest in flight) ----------
    const size_t f = gtid * 3;
    f4 P0 = __builtin_nontemporal_load(pp4 + f);
    f4 P1 = __builtin_nontemporal_load(pp4 + f + 1);
    f4 P2 = __builtin_nontemporal_load(pp4 + f + 2);
    f4 T0 = __builtin_nontemporal_load(tp4 + f);
    f4 T1 = __builtin_nontemporal_load(tp4 + f + 1);
    f4 T2 = __builtin_nontemporal_load(tp4 + f + 2);

    float accc = 0.0f;   // class MSE partial
    float accp = 0.0f;   // pose partial

    // ---------- class trips 0..3 ----------
    #pragma unroll 2
    for (int k = 0; k < CTRIPS / 2; ++k) {
        const size_t i = gtid + (size_t)k * G;
        f4 p = __builtin_nontemporal_load(pc4 + i);
        f4 t = __builtin_nontemporal_load(tc4 + i);
        f4 d = p - t;
        accc += d.x * d.x + d.y * d.y + d.z * d.z + d.w * d.w;
    }

    // ---------- pose element A (trig overlaps trips 4..7 load issue) ----------
    accp += pose_elem(P0.x, P0.y, P0.z, P0.w, P1.x, P1.y,
                      T0.x, T0.y, T0.z, T0.w, T1.x, T1.y);

    // ---------- class trips 4..7 ----------
    #pragma unroll 2
    for (int k = CTRIPS / 2; k < CTRIPS; ++k) {
        const size_t i = gtid + (size_t)k * G;
        f4 p = __builtin_nontemporal_load(pc4 + i);
        f4 t = __builtin_nontemporal_load(tc4 + i);
        f4 d = p - t;
        accc += d.x * d.x + d.y * d.y + d.z * d.z + d.w * d.w;
    }

    // ---------- pose element B ----------
    accp += pose_elem(P1.z, P1.w, P2.x, P2.y, P2.z, P2.w,
                      T1.z, T1.w, T2.x, T2.y, T2.z, T2.w);

    // ---------- paired block reduction ----------
    #pragma unroll
    for (int off = 32; off > 0; off >>= 1) {
        accc += __shfl_down(accc, off);
        accp += __shfl_down(accp, off);
    }
    __shared__ float red_c[4], red_p[4];
    const int lane = tid & 63, wave = tid >> 6;
    if (lane == 0) { red_c[wave] = accc; red_p[wave] = accp; }
    __syncthreads();
    if (tid == 0) {
        ws[b]          = red_c[0] + red_c[1] + red_c[2] + red_c[3];
        ws[BLOCKS + b] = red_p[0] + red_p[1] + red_p[2] + red_p[3];
    }
}

// finalize: ws[0..BLOCKS) = class partials, ws[BLOCKS..2*BLOCKS) = pose partials
__global__ __launch_bounds__(THREADS) void pose_loss_finalize(
    const float* __restrict__ ws, float* __restrict__ out,
    float inv_pose, float inv_class)
{
    float c = 0.0f, p = 0.0f;
    for (int k = threadIdx.x; k < BLOCKS; k += THREADS) {
        c += ws[k];
        p += ws[BLOCKS + k];
    }
    #pragma unroll
    for (int off = 32; off > 0; off >>= 1) {
        p += __shfl_down(p, off);
        c += __shfl_down(c, off);
    }
    __shared__ float r_p[4], r_c[4];
    const int lane = threadIdx.x & 63, wave = threadIdx.x >> 6;
    if (lane == 0) { r_p[wave] = p; r_c[wave] = c; }
    __syncthreads();
    if (threadIdx.x == 0) {
        float lp = (r_p[0] + r_p[1] + r_p[2] + r_p[3]) * inv_pose;
        float lc = (r_c[0] + r_c[1] + r_c[2] + r_c[3]) * inv_class;
        out[0] = lp + lc;
        out[1] = lp;
        out[2] = lc;
    }
}

extern "C" void kernel_launch(void* const* d_in, const int* in_sizes, int n_in,
                              void* d_out, int out_size, void* d_ws, size_t ws_size,
                              hipStream_t stream) {
    const f4* pred_pose    = (const f4*)d_in[0];
    const f4* pred_class   = (const f4*)d_in[1];
    const f4* target_pose  = (const f4*)d_in[2];
    const f4* target_class = (const f4*)d_in[3];
    float* out = (float*)d_out;
    float* ws  = (float*)d_ws;

    const int B = in_sizes[0] / 6;   // 1048576; kernel constants assume this

    pose_loss_fused<<<BLOCKS, THREADS, 0, stream>>>(
        pred_pose, pred_class, target_pose, target_class, ws);

    const float inv_pose  = 1.0f / (8.0f  * (float)B);
    const float inv_class = 1.0f / (16.0f * (float)B);
    pose_loss_finalize<<<1, THREADS, 0, stream>>>(ws, out, inv_pose, inv_class);
}